// Round 15
// baseline (371.878 us; speedup 1.0000x reference)
//
#include <hip/hip_runtime.h>

typedef unsigned short u16;
typedef float f32x4 __attribute__((ext_vector_type(4)));
typedef __bf16 bf16x8 __attribute__((ext_vector_type(8)));

__device__ __forceinline__ u16 f2bf(float f) {
  unsigned u = __float_as_uint(f);
  u += 0x7fffu + ((u >> 16) & 1u);
  return (u16)(u >> 16);
}

__device__ __forceinline__ float bf2f(u16 h) {
  return __uint_as_float((unsigned)h << 16);
}

__device__ __forceinline__ f32x4 mfma16(bf16x8 a, bf16x8 b, f32x4 c) {
  return __builtin_amdgcn_mfma_f32_16x16x32_bf16(a, b, c, 0, 0, 0);
}

// async global->LDS, 16B per lane; lds dest is wave-uniform base + lane*16
#define GLDS16(gp, lp)                                                            \
  __builtin_amdgcn_global_load_lds((const __attribute__((address_space(1))) void*)(gp), \
                                   (__attribute__((address_space(3))) void*)(lp), 16, 0, 0)

// ---------------------------------------------------------------------------
// prep_all: all weight transposes (f32 [R][C] -> bf16 [C][R]) in ONE launch.
// ---------------------------------------------------------------------------
__global__ __launch_bounds__(256) void prep_all(const float* __restrict__ Wq,
                                                const float* __restrict__ Wk,
                                                const float* __restrict__ Wv,
                                                const float* __restrict__ Wo,
                                                const float* __restrict__ W1,
                                                const float* __restrict__ W2,
                                                u16* __restrict__ Wqkvt, u16* __restrict__ Wot,
                                                u16* __restrict__ W1t, u16* __restrict__ W2t) {
  __shared__ float t[32][33];
  const int bid = blockIdx.x;
  const float* in;
  u16* out;
  int R, C, bx, by;
  if (bid < 256) {
    in = Wq; out = Wqkvt; R = 512; C = 512; bx = bid & 15; by = bid >> 4;
  } else if (bid < 512) {
    in = Wk; out = Wqkvt + 262144; R = 512; C = 512; bx = (bid - 256) & 15; by = (bid - 256) >> 4;
  } else if (bid < 768) {
    in = Wv; out = Wqkvt + 524288; R = 512; C = 512; bx = (bid - 512) & 15; by = (bid - 512) >> 4;
  } else if (bid < 1024) {
    in = Wo; out = Wot; R = 512; C = 512; bx = (bid - 768) & 15; by = (bid - 768) >> 4;
  } else if (bid < 2048) {
    in = W1; out = W1t; R = 512; C = 2048; bx = (bid - 1024) & 63; by = (bid - 1024) >> 6;
  } else {
    in = W2; out = W2t; R = 2048; C = 512; bx = (bid - 2048) & 15; by = (bid - 2048) >> 4;
  }
  const int c0 = bx * 32, r0 = by * 32;
  const int tx = threadIdx.x & 31, ty = threadIdx.x >> 5;
#pragma unroll
  for (int j = 0; j < 4; ++j)
    t[ty * 4 + j][tx] = in[(size_t)(r0 + ty * 4 + j) * C + c0 + tx];
  __syncthreads();
#pragma unroll
  for (int j = 0; j < 4; ++j)
    out[(size_t)(c0 + ty * 4 + j) * R + r0 + tx] = f2bf(t[tx][ty * 4 + j]);
}

// ---------------------------------------------------------------------------
// LayerNorm: x (f32 or bf16) [R][512] -> out bf16 [R][512].
// 1 wave per row, 4 rows/block.
// ---------------------------------------------------------------------------
template <int IN_BF16>
__global__ __launch_bounds__(256) void ln_fwd(const void* __restrict__ xin,
                                              const float* __restrict__ gw,
                                              const float* __restrict__ bw,
                                              u16* __restrict__ out) {
  int row = blockIdx.x * 4 + (threadIdx.x >> 6);
  int lane = threadIdx.x & 63;
  float xv[8], gv[8], bv[8];
  if (IN_BF16) {
    const u16* xr = (const u16*)xin + (size_t)row * 512 + lane * 8;
    union { uint4 u; u16 h[8]; } r;
    r.u = *(const uint4*)xr;
#pragma unroll
    for (int j = 0; j < 8; ++j) xv[j] = bf2f(r.h[j]);
  } else {
    const float* xr = (const float*)xin + (size_t)row * 512 + lane * 8;
    *(float4*)&xv[0] = *(const float4*)xr;
    *(float4*)&xv[4] = *(const float4*)(xr + 4);
  }
  *(float4*)&gv[0] = *(const float4*)(gw + lane * 8);
  *(float4*)&gv[4] = *(const float4*)(gw + lane * 8 + 4);
  *(float4*)&bv[0] = *(const float4*)(bw + lane * 8);
  *(float4*)&bv[4] = *(const float4*)(bw + lane * 8 + 4);
  float sum = 0.f, sq = 0.f;
#pragma unroll
  for (int j = 0; j < 8; ++j) { sum += xv[j]; sq += xv[j] * xv[j]; }
#pragma unroll
  for (int d = 1; d < 64; d <<= 1) {
    sum += __shfl_xor(sum, d);
    sq += __shfl_xor(sq, d);
  }
  float mean = sum * (1.f / 512.f);
  float var = sq * (1.f / 512.f) - mean * mean;
  float rstd = rsqrtf(var + 1e-5f);
  union { uint4 u; u16 h[8]; } ob;
#pragma unroll
  for (int j = 0; j < 8; ++j)
    ob.h[j] = f2bf((xv[j] - mean) * rstd * gv[j] + bv[j]);
  *(uint4*)(out + (size_t)row * 512 + lane * 8) = ob.u;
}

// ---------------------------------------------------------------------------
// GEMM: C[M][N] = A[M][K](bf16, lda) * Bt[N][K](bf16, ldb)^T, batched over z.
// EPI 1: QKV fused: bf16 = acc + bias(q|k|v per col>>9); cols>=1024 write
//        V TRANSPOSED into vtg[b][col-1024][row]
// EPI 2: out bf16 = gelu(acc + bias)        (MLP1, tanh-form)
// EPI 4: out bf16 = acc / rowsum(A)         (PV; rowsum via ones-B MFMA)
// EPI 5: out bf16 = exp(acc / sqrt(512))    (QK -> unnormalized softmax)
// EPI 6: out bf16 = acc + bias + res(f32)   (Wo-proj -> x1 bf16)
// EPI 7: out f32  = acc + bias + res(bf16)  (MLP2 + x1 residual)
// SWZ 1: bijective XCD-aware block remap (requires total blocks % 8 == 0)
// 128x128 tile, BK=64, 256 thr (4 waves 2x2). LDS: K-panel split
// [panel=k/32][128 rows][32 elems]; As[p*4096 + r*32 + c] = A[m0+r][k0+p*32+c]
// (R9/R13-proven schedule; inner loop untouched.)
// ---------------------------------------------------------------------------
template <int EPI, int SWZ>
__global__ __launch_bounds__(256, 2) void gemm_bt(const u16* __restrict__ A, int lda, size_t sA,
                                                  const u16* __restrict__ Bt, int ldb, size_t sB,
                                                  const float* __restrict__ bias,
                                                  const float* __restrict__ bias1,
                                                  const float* __restrict__ bias2,
                                                  const void* __restrict__ res,
                                                  u16* __restrict__ vtg,
                                                  void* __restrict__ out, int ldc, size_t sC,
                                                  int M, int N, int K) {
  __shared__ u16 As[128 * 64];
  __shared__ u16 Bs[128 * 64];
  const int tid = threadIdx.x;
  const int lane = tid & 63, w = tid >> 6;
  const int wr = w >> 1, wc = w & 1;
  const int lh = lane >> 4, ll = lane & 15;

  int bx = blockIdx.x, by = blockIdx.y, bz = blockIdx.z;
  if (SWZ) {
    const int gx = gridDim.x, gy = gridDim.y;
    const int nwg = gx * gy * gridDim.z;
    const int lid = bx + gx * (by + gy * bz);
    const int cpx = nwg >> 3;  // nwg % 8 == 0 at all SWZ call sites
    const int s = (lid & 7) * cpx + (lid >> 3);
    bx = s % gx;
    const int r2 = s / gx;
    by = r2 % gy;
    bz = r2 / gy;
  }
  const int m0 = bx * 128, n0 = by * 128;
  A += (size_t)bz * sA;
  Bt += (size_t)bz * sB;

  // staging: block t = w*4+j covers panel (t>>3), rows (t&7)*16 + (lane>>2),
  // elems (t>>3)*32 + (lane&3)*8; dest = linear 1024B at As/Bs + t*512
  const int srow = lane >> 2;
  const int scol = (lane & 3) * 8;
  const u16* ga = A + (size_t)(m0 + srow) * lda + scol;
  const u16* gb = Bt + (size_t)(n0 + srow) * ldb + scol;

  // all-ones B fragment for inline row-sum (EPI 4)
  bf16x8 ones;
#pragma unroll
  for (int j = 0; j < 8; ++j) ones[j] = (__bf16)1.0f;

  f32x4 acc[4][4] = {};
  f32x4 accs[4] = {};
  const int nk = K >> 6;
  for (int kt = 0; kt < nk; ++kt) {
    const int k0 = kt << 6;
#pragma unroll
    for (int j = 0; j < 4; ++j) {
      const int t = w * 4 + j;
      const int radd = (t & 7) * 16;
      const int kadd = (t >> 3) * 32;
      GLDS16(ga + (size_t)radd * lda + k0 + kadd, &As[t * 512]);
      GLDS16(gb + (size_t)radd * ldb + k0 + kadd, &Bs[t * 512]);
    }
    __syncthreads();
#pragma unroll
    for (int ks = 0; ks < 2; ++ks) {
      bf16x8 a[4], b[4];
#pragma unroll
      for (int m = 0; m < 4; ++m)
        a[m] = *(const bf16x8*)&As[ks * 4096 + (wr * 64 + m * 16 + ll) * 32 + lh * 8];
#pragma unroll
      for (int n = 0; n < 4; ++n)
        b[n] = *(const bf16x8*)&Bs[ks * 4096 + (wc * 64 + n * 16 + ll) * 32 + lh * 8];
#pragma unroll
      for (int m = 0; m < 4; ++m)
#pragma unroll
        for (int n = 0; n < 4; ++n)
          acc[m][n] = mfma16(a[m], b[n], acc[m][n]);
      if (EPI == 4) {
#pragma unroll
        for (int m = 0; m < 4; ++m) accs[m] = mfma16(a[m], ones, accs[m]);
      }
    }
    __syncthreads();
  }

  // epilogue (C/D layout: col = lane&15, row = (lane>>4)*4 + i, verified m89)
  u16* outh = (u16*)out + (size_t)bz * sC;
  float* outf = (float*)out + (size_t)bz * sC;
#pragma unroll
  for (int m = 0; m < 4; ++m) {
    int row = m0 + wr * 64 + m * 16 + lh * 4;
#pragma unroll
    for (int n = 0; n < 4; ++n) {
      int col = n0 + wc * 64 + n * 16 + ll;
      float bv = 0.f;
      if (EPI == 1) {
        const float* bp = (col < 512) ? bias : (col < 1024 ? bias1 : bias2);
        bv = bp[col & 511];
      } else if (EPI == 2 || EPI == 6 || EPI == 7) {
        bv = bias[col];
      }
      if (EPI == 1 && col >= 1024) {
        union { uint2 u; u16 h[4]; } pk;
#pragma unroll
        for (int i = 0; i < 4; ++i) pk.h[i] = f2bf(acc[m][n][i] + bv);
        const int b = row >> 12, brow = row & 4095;
        *(uint2*)&vtg[((size_t)(b * 512 + (col - 1024))) * 4096 + brow] = pk.u;
      } else {
#pragma unroll
        for (int i = 0; i < 4; ++i) {
          float v = acc[m][n][i] + bv;
          size_t idx = (size_t)(row + i) * ldc + col;
          if (EPI == 2) {
            // tanh-form gelu; max dev from erf-gelu ~3e-4 << bf16 ulp of m1
            float y = 0.7978845608028654f * (v + 0.044715f * v * v * v);
            v = v / (1.f + __expf(-2.f * y));
          }
          if (EPI == 4) v = v * (1.f / accs[m][i]);   // rowsum > 0 always
          if (EPI == 5) v = __expf(v * 0.044194173824159216f);  // 512^-0.5
          if (EPI == 6) {
            outh[idx] = f2bf(v + ((const float*)res)[idx]);
          } else if (EPI == 7) {
            outf[idx] = v + bf2f(((const u16*)res)[idx]);
          } else {
            outh[idx] = f2bf(v);
          }
        }
      }
    }
  }
}

// ---------------------------------------------------------------------------
extern "C" void kernel_launch(void* const* d_in, const int* in_sizes, int n_in,
                              void* d_out, int out_size, void* d_ws, size_t ws_size,
                              hipStream_t stream) {
  const float* x     = (const float*)d_in[0];
  const float* ln1g  = (const float*)d_in[1];
  const float* ln1b  = (const float*)d_in[2];
  const float* Wq    = (const float*)d_in[3];
  const float* bq    = (const float*)d_in[4];
  const float* Wk    = (const float*)d_in[5];
  const float* bk    = (const float*)d_in[6];
  const float* Wv    = (const float*)d_in[7];
  const float* bVv   = (const float*)d_in[8];
  const float* Wo    = (const float*)d_in[9];
  const float* bo    = (const float*)d_in[10];
  const float* ln2g  = (const float*)d_in[11];
  const float* ln2b  = (const float*)d_in[12];
  const float* W1    = (const float*)d_in[13];
  const float* b1    = (const float*)d_in[14];
  const float* W2    = (const float*)d_in[15];
  const float* b2    = (const float*)d_in[16];

  char* base = (char*)d_ws;
  u16* Wqkvt = (u16*)base;                      // [1536][512]
  u16* Wot   = Wqkvt + 786432;                  // [512][512]
  u16* W1t   = Wot + 262144;                    // [2048][512]
  u16* W2t   = W1t + 1048576;                   // [512][2048]
  u16* qkvb = (u16*)(base + (8ull << 20));      // [16384][1536] bf16 (V region unused)
  u16* Vt   = qkvb + (size_t)16384 * 1536;      // [4][512][4096] bf16
  u16* m1   = qkvb;                             // alias (qkv+Vt dead by MLP)
  u16* hb   = (u16*)(base + (72ull << 20));     // h/o/h2 [16384][512] bf16
  const size_t sco_off = 88ull << 20;
  u16* scores = (u16*)(base + sco_off);         // [nb][4096][4096] bf16 (exp-scores)
  u16* x1h = scores;                            // alias: [16384][512] bf16 (scores dead by Wo)

  const size_t S = 4096;
  const size_t per_b = S * S * 2;
  int nb = 1;
  if (ws_size >= sco_off + 4 * per_b) nb = 4;
  else if (ws_size >= sco_off + 2 * per_b) nb = 2;

  prep_all<<<3072, 256, 0, stream>>>(Wq, Wk, Wv, Wo, W1, W2, Wqkvt, Wot, W1t, W2t);

  // h = LN1(x)
  ln_fwd<0><<<4096, 256, 0, stream>>>(x, ln1g, ln1b, hb);
  // qkv = h @ Wqkv + b; V written transposed straight into Vt  (swizzled, 1536 blocks)
  gemm_bt<1, 1><<<dim3(128, 12, 1), 256, 0, stream>>>(hb, 512, 0, Wqkvt, 512, 0,
                                                      bq, bk, bVv, nullptr, Vt,
                                                      qkvb, 1536, 0, 16384, 1536, 512);

  // attention: QK writes exp-scores; PV normalizes via inline ones-MFMA rowsum.
  for (int b0 = 0; b0 < 4; b0 += nb) {
    int nz = (4 - b0) < nb ? (4 - b0) : nb;
    const u16* qk = qkvb + (size_t)b0 * S * 1536;
    // scores[z] = exp(Q @ K^T * scale)   (bf16, unnormalized; swizzled grid)
    gemm_bt<5, 1><<<dim3(32, 32, nz), 256, 0, stream>>>(qk, 1536, S * 1536, qk + 512, 1536, S * 1536,
                                                        nullptr, nullptr, nullptr, nullptr, nullptr,
                                                        scores, 4096, S * S, 4096, 4096, 512);
    // O[z] = (P~ @ V) / rowsum(P~)
    gemm_bt<4, 0><<<dim3(32, 4, nz), 256, 0, stream>>>(scores, 4096, S * S,
                                                       Vt + (size_t)b0 * 512 * S, 4096, 512 * S,
                                                       nullptr, nullptr, nullptr, nullptr, nullptr,
                                                       hb + (size_t)b0 * S * 512, 512, S * 512,
                                                       4096, 512, 4096);
  }

  // x1 = bf16(x + o @ Wo + bo)   (bf16 residual stream)
  gemm_bt<6, 0><<<dim3(128, 4, 1), 256, 0, stream>>>(hb, 512, 0, Wot, 512, 0,
                                                     bo, nullptr, nullptr, x, nullptr,
                                                     x1h, 512, 0, 16384, 512, 512);
  // h2 = LN2(x1)   (bf16 input)
  ln_fwd<1><<<4096, 256, 0, stream>>>(x1h, ln2g, ln2b, hb);
  // m1 = gelu(h2 @ W1 + b1)   (swizzled, 2048 blocks)
  gemm_bt<2, 1><<<dim3(128, 16, 1), 256, 0, stream>>>(hb, 512, 0, W1t, 512, 0,
                                                      b1, nullptr, nullptr, nullptr, nullptr,
                                                      m1, 2048, 0, 16384, 2048, 512);
  // out = x1 + m1 @ W2 + b2
  gemm_bt<7, 0><<<dim3(128, 4, 1), 256, 0, stream>>>(m1, 2048, 0, W2t, 2048, 0,
                                                     b2, nullptr, nullptr, x1h, nullptr,
                                                     (float*)d_out, 512, 0, 16384, 512, 2048);
}

// Round 16
// 350.623 us; speedup vs baseline: 1.0606x; 1.0606x over previous
//
#include <hip/hip_runtime.h>

typedef unsigned short u16;
typedef float f32x4 __attribute__((ext_vector_type(4)));
typedef __bf16 bf16x8 __attribute__((ext_vector_type(8)));

__device__ __forceinline__ u16 f2bf(float f) {
  unsigned u = __float_as_uint(f);
  u += 0x7fffu + ((u >> 16) & 1u);
  return (u16)(u >> 16);
}

__device__ __forceinline__ float bf2f(u16 h) {
  return __uint_as_float((unsigned)h << 16);
}

__device__ __forceinline__ f32x4 mfma16(bf16x8 a, bf16x8 b, f32x4 c) {
  return __builtin_amdgcn_mfma_f32_16x16x32_bf16(a, b, c, 0, 0, 0);
}

// async global->LDS, 16B per lane; lds dest is wave-uniform base + lane*16
#define GLDS16(gp, lp)                                                            \
  __builtin_amdgcn_global_load_lds((const __attribute__((address_space(1))) void*)(gp), \
                                   (__attribute__((address_space(3))) void*)(lp), 16, 0, 0)

// ---------------------------------------------------------------------------
// prep_all: all weight transposes (f32 [R][C] -> bf16 [C][R]) in ONE launch.
// ---------------------------------------------------------------------------
__global__ __launch_bounds__(256) void prep_all(const float* __restrict__ Wq,
                                                const float* __restrict__ Wk,
                                                const float* __restrict__ Wv,
                                                const float* __restrict__ Wo,
                                                const float* __restrict__ W1,
                                                const float* __restrict__ W2,
                                                u16* __restrict__ Wqkvt, u16* __restrict__ Wot,
                                                u16* __restrict__ W1t, u16* __restrict__ W2t) {
  __shared__ float t[32][33];
  const int bid = blockIdx.x;
  const float* in;
  u16* out;
  int R, C, bx, by;
  if (bid < 256) {
    in = Wq; out = Wqkvt; R = 512; C = 512; bx = bid & 15; by = bid >> 4;
  } else if (bid < 512) {
    in = Wk; out = Wqkvt + 262144; R = 512; C = 512; bx = (bid - 256) & 15; by = (bid - 256) >> 4;
  } else if (bid < 768) {
    in = Wv; out = Wqkvt + 524288; R = 512; C = 512; bx = (bid - 512) & 15; by = (bid - 512) >> 4;
  } else if (bid < 1024) {
    in = Wo; out = Wot; R = 512; C = 512; bx = (bid - 768) & 15; by = (bid - 768) >> 4;
  } else if (bid < 2048) {
    in = W1; out = W1t; R = 512; C = 2048; bx = (bid - 1024) & 63; by = (bid - 1024) >> 6;
  } else {
    in = W2; out = W2t; R = 2048; C = 512; bx = (bid - 2048) & 15; by = (bid - 2048) >> 4;
  }
  const int c0 = bx * 32, r0 = by * 32;
  const int tx = threadIdx.x & 31, ty = threadIdx.x >> 5;
#pragma unroll
  for (int j = 0; j < 4; ++j)
    t[ty * 4 + j][tx] = in[(size_t)(r0 + ty * 4 + j) * C + c0 + tx];
  __syncthreads();
#pragma unroll
  for (int j = 0; j < 4; ++j)
    out[(size_t)(c0 + ty * 4 + j) * R + r0 + tx] = f2bf(t[tx][ty * 4 + j]);
}

// ---------------------------------------------------------------------------
// LayerNorm: x (f32 or bf16) [R][512] -> out bf16 [R][512].
// 1 wave per row, 4 rows/block.
// ---------------------------------------------------------------------------
template <int IN_BF16>
__global__ __launch_bounds__(256) void ln_fwd(const void* __restrict__ xin,
                                              const float* __restrict__ gw,
                                              const float* __restrict__ bw,
                                              u16* __restrict__ out) {
  int row = blockIdx.x * 4 + (threadIdx.x >> 6);
  int lane = threadIdx.x & 63;
  float xv[8], gv[8], bv[8];
  if (IN_BF16) {
    const u16* xr = (const u16*)xin + (size_t)row * 512 + lane * 8;
    union { uint4 u; u16 h[8]; } r;
    r.u = *(const uint4*)xr;
#pragma unroll
    for (int j = 0; j < 8; ++j) xv[j] = bf2f(r.h[j]);
  } else {
    const float* xr = (const float*)xin + (size_t)row * 512 + lane * 8;
    *(float4*)&xv[0] = *(const float4*)xr;
    *(float4*)&xv[4] = *(const float4*)(xr + 4);
  }
  *(float4*)&gv[0] = *(const float4*)(gw + lane * 8);
  *(float4*)&gv[4] = *(const float4*)(gw + lane * 8 + 4);
  *(float4*)&bv[0] = *(const float4*)(bw + lane * 8);
  *(float4*)&bv[4] = *(const float4*)(bw + lane * 8 + 4);
  float sum = 0.f, sq = 0.f;
#pragma unroll
  for (int j = 0; j < 8; ++j) { sum += xv[j]; sq += xv[j] * xv[j]; }
#pragma unroll
  for (int d = 1; d < 64; d <<= 1) {
    sum += __shfl_xor(sum, d);
    sq += __shfl_xor(sq, d);
  }
  float mean = sum * (1.f / 512.f);
  float var = sq * (1.f / 512.f) - mean * mean;
  float rstd = rsqrtf(var + 1e-5f);
  union { uint4 u; u16 h[8]; } ob;
#pragma unroll
  for (int j = 0; j < 8; ++j)
    ob.h[j] = f2bf((xv[j] - mean) * rstd * gv[j] + bv[j]);
  *(uint4*)(out + (size_t)row * 512 + lane * 8) = ob.u;
}

// ---------------------------------------------------------------------------
// GEMM: C[M][N] = A[M][K](bf16, lda) * Bt[N][K](bf16, ldb)^T, batched over z.
// EPI 1: QKV fused: bf16 = acc + bias(q|k|v per col>>9); cols>=1024 write
//        V TRANSPOSED into vtg[b][col-1024][row]
// EPI 2: out bf16 = gelu(acc + bias)        (MLP1, tanh-form)
// EPI 4: out bf16 = acc / rowsum(A)         (PV; rowsum via ones-B MFMA)
// EPI 5: out bf16 = exp(acc / sqrt(512))    (QK -> unnormalized softmax)
// EPI 6: out bf16 = acc + bias + res(f32)   (Wo-proj -> x1 bf16)
// EPI 7: out f32  = acc + bias + res(bf16)  (MLP2 + x1 residual)
// 128x128 tile, BK=64, 256 thr (4 waves 2x2). LDS: K-panel split
// [panel=k/32][128 rows][32 elems]; As[p*4096 + r*32 + c] = A[m0+r][k0+p*32+c]
// (R9/R13-proven schedule; inner loop untouched.)
// ---------------------------------------------------------------------------
template <int EPI>
__global__ __launch_bounds__(256, 2) void gemm_bt(const u16* __restrict__ A, int lda, size_t sA,
                                                  const u16* __restrict__ Bt, int ldb, size_t sB,
                                                  const float* __restrict__ bias,
                                                  const float* __restrict__ bias1,
                                                  const float* __restrict__ bias2,
                                                  const void* __restrict__ res,
                                                  u16* __restrict__ vtg,
                                                  void* __restrict__ out, int ldc, size_t sC,
                                                  int M, int N, int K) {
  __shared__ u16 As[128 * 64];
  __shared__ u16 Bs[128 * 64];
  const int tid = threadIdx.x;
  const int lane = tid & 63, w = tid >> 6;
  const int wr = w >> 1, wc = w & 1;
  const int m0 = blockIdx.x * 128, n0 = blockIdx.y * 128;
  const int lh = lane >> 4, ll = lane & 15;
  A += (size_t)blockIdx.z * sA;
  Bt += (size_t)blockIdx.z * sB;

  // staging: block t = w*4+j covers panel (t>>3), rows (t&7)*16 + (lane>>2),
  // elems (t>>3)*32 + (lane&3)*8; dest = linear 1024B at As/Bs + t*512
  const int srow = lane >> 2;
  const int scol = (lane & 3) * 8;
  const u16* ga = A + (size_t)(m0 + srow) * lda + scol;
  const u16* gb = Bt + (size_t)(n0 + srow) * ldb + scol;

  // all-ones B fragment for inline row-sum (EPI 4)
  bf16x8 ones;
#pragma unroll
  for (int j = 0; j < 8; ++j) ones[j] = (__bf16)1.0f;

  f32x4 acc[4][4] = {};
  f32x4 accs[4] = {};
  const int nk = K >> 6;
  for (int kt = 0; kt < nk; ++kt) {
    const int k0 = kt << 6;
#pragma unroll
    for (int j = 0; j < 4; ++j) {
      const int t = w * 4 + j;
      const int radd = (t & 7) * 16;
      const int kadd = (t >> 3) * 32;
      GLDS16(ga + (size_t)radd * lda + k0 + kadd, &As[t * 512]);
      GLDS16(gb + (size_t)radd * ldb + k0 + kadd, &Bs[t * 512]);
    }
    __syncthreads();
#pragma unroll
    for (int ks = 0; ks < 2; ++ks) {
      bf16x8 a[4], b[4];
#pragma unroll
      for (int m = 0; m < 4; ++m)
        a[m] = *(const bf16x8*)&As[ks * 4096 + (wr * 64 + m * 16 + ll) * 32 + lh * 8];
#pragma unroll
      for (int n = 0; n < 4; ++n)
        b[n] = *(const bf16x8*)&Bs[ks * 4096 + (wc * 64 + n * 16 + ll) * 32 + lh * 8];
#pragma unroll
      for (int m = 0; m < 4; ++m)
#pragma unroll
        for (int n = 0; n < 4; ++n)
          acc[m][n] = mfma16(a[m], b[n], acc[m][n]);
      if (EPI == 4) {
#pragma unroll
        for (int m = 0; m < 4; ++m) accs[m] = mfma16(a[m], ones, accs[m]);
      }
    }
    __syncthreads();
  }

  // epilogue (C/D layout: col = lane&15, row = (lane>>4)*4 + i, verified m89)
  u16* outh = (u16*)out + (size_t)blockIdx.z * sC;
  float* outf = (float*)out + (size_t)blockIdx.z * sC;
#pragma unroll
  for (int m = 0; m < 4; ++m) {
    int row = m0 + wr * 64 + m * 16 + lh * 4;
#pragma unroll
    for (int n = 0; n < 4; ++n) {
      int col = n0 + wc * 64 + n * 16 + ll;
      float bv = 0.f;
      if (EPI == 1) {
        const float* bp = (col < 512) ? bias : (col < 1024 ? bias1 : bias2);
        bv = bp[col & 511];
      } else if (EPI == 2 || EPI == 6 || EPI == 7) {
        bv = bias[col];
      }
      if (EPI == 1 && col >= 1024) {
        union { uint2 u; u16 h[4]; } pk;
#pragma unroll
        for (int i = 0; i < 4; ++i) pk.h[i] = f2bf(acc[m][n][i] + bv);
        const int b = row >> 12, brow = row & 4095;
        *(uint2*)&vtg[((size_t)(b * 512 + (col - 1024))) * 4096 + brow] = pk.u;
      } else {
#pragma unroll
        for (int i = 0; i < 4; ++i) {
          float v = acc[m][n][i] + bv;
          size_t idx = (size_t)(row + i) * ldc + col;
          if (EPI == 2) {
            // tanh-form gelu; max dev from erf-gelu ~3e-4 << bf16 ulp of m1
            float y = 0.7978845608028654f * (v + 0.044715f * v * v * v);
            v = v / (1.f + __expf(-2.f * y));
          }
          if (EPI == 4) v = v * (1.f / accs[m][i]);   // rowsum > 0 always
          if (EPI == 5) v = __expf(v * 0.044194173824159216f);  // 512^-0.5
          if (EPI == 6) {
            outh[idx] = f2bf(v + ((const float*)res)[idx]);
          } else if (EPI == 7) {
            outf[idx] = v + bf2f(((const u16*)res)[idx]);
          } else {
            outh[idx] = f2bf(v);
          }
        }
      }
    }
  }
}

// ---------------------------------------------------------------------------
extern "C" void kernel_launch(void* const* d_in, const int* in_sizes, int n_in,
                              void* d_out, int out_size, void* d_ws, size_t ws_size,
                              hipStream_t stream) {
  const float* x     = (const float*)d_in[0];
  const float* ln1g  = (const float*)d_in[1];
  const float* ln1b  = (const float*)d_in[2];
  const float* Wq    = (const float*)d_in[3];
  const float* bq    = (const float*)d_in[4];
  const float* Wk    = (const float*)d_in[5];
  const float* bk    = (const float*)d_in[6];
  const float* Wv    = (const float*)d_in[7];
  const float* bVv   = (const float*)d_in[8];
  const float* Wo    = (const float*)d_in[9];
  const float* bo    = (const float*)d_in[10];
  const float* ln2g  = (const float*)d_in[11];
  const float* ln2b  = (const float*)d_in[12];
  const float* W1    = (const float*)d_in[13];
  const float* b1    = (const float*)d_in[14];
  const float* W2    = (const float*)d_in[15];
  const float* b2    = (const float*)d_in[16];

  char* base = (char*)d_ws;
  u16* Wqkvt = (u16*)base;                      // [1536][512]
  u16* Wot   = Wqkvt + 786432;                  // [512][512]
  u16* W1t   = Wot + 262144;                    // [2048][512]
  u16* W2t   = W1t + 1048576;                   // [512][2048]
  u16* qkvb = (u16*)(base + (8ull << 20));      // [16384][1536] bf16 (V region unused)
  u16* Vt   = qkvb + (size_t)16384 * 1536;      // [4][512][4096] bf16
  u16* m1   = qkvb;                             // alias (qkv+Vt dead by MLP)
  u16* hb   = (u16*)(base + (72ull << 20));     // h/o/h2 [16384][512] bf16
  const size_t sco_off = 88ull << 20;
  u16* scores = (u16*)(base + sco_off);         // [nb][4096][4096] bf16 (exp-scores)
  u16* x1h = scores;                            // alias: [16384][512] bf16 (scores dead by Wo)

  const size_t S = 4096;
  const size_t per_b = S * S * 2;
  int nb = 1;
  if (ws_size >= sco_off + 4 * per_b) nb = 4;
  else if (ws_size >= sco_off + 2 * per_b) nb = 2;

  prep_all<<<3072, 256, 0, stream>>>(Wq, Wk, Wv, Wo, W1, W2, Wqkvt, Wot, W1t, W2t);

  // h = LN1(x)
  ln_fwd<0><<<4096, 256, 0, stream>>>(x, ln1g, ln1b, hb);
  // qkv = h @ Wqkv + b; V written transposed straight into Vt
  gemm_bt<1><<<dim3(128, 12, 1), 256, 0, stream>>>(hb, 512, 0, Wqkvt, 512, 0,
                                                   bq, bk, bVv, nullptr, Vt,
                                                   qkvb, 1536, 0, 16384, 1536, 512);

  // attention: QK writes exp-scores; PV normalizes via inline ones-MFMA rowsum.
  for (int b0 = 0; b0 < 4; b0 += nb) {
    int nz = (4 - b0) < nb ? (4 - b0) : nb;
    const u16* qk = qkvb + (size_t)b0 * S * 1536;
    // scores[z] = exp(Q @ K^T * scale)   (bf16, unnormalized)
    gemm_bt<5><<<dim3(32, 32, nz), 256, 0, stream>>>(qk, 1536, S * 1536, qk + 512, 1536, S * 1536,
                                                     nullptr, nullptr, nullptr, nullptr, nullptr,
                                                     scores, 4096, S * S, 4096, 4096, 512);
    // O[z] = (P~ @ V) / rowsum(P~)
    gemm_bt<4><<<dim3(32, 4, nz), 256, 0, stream>>>(scores, 4096, S * S,
                                                    Vt + (size_t)b0 * 512 * S, 4096, 512 * S,
                                                    nullptr, nullptr, nullptr, nullptr, nullptr,
                                                    hb + (size_t)b0 * S * 512, 512, S * 512,
                                                    4096, 512, 4096);
  }

  // x1 = bf16(x + o @ Wo + bo)   (bf16 residual stream)
  gemm_bt<6><<<dim3(128, 4, 1), 256, 0, stream>>>(hb, 512, 0, Wot, 512, 0,
                                                  bo, nullptr, nullptr, x, nullptr,
                                                  x1h, 512, 0, 16384, 512, 512);
  // h2 = LN2(x1)   (bf16 input)
  ln_fwd<1><<<4096, 256, 0, stream>>>(x1h, ln2g, ln2b, hb);
  // m1 = gelu(h2 @ W1 + b1)
  gemm_bt<2><<<dim3(128, 16, 1), 256, 0, stream>>>(hb, 512, 0, W1t, 512, 0,
                                                   b1, nullptr, nullptr, nullptr, nullptr,
                                                   m1, 2048, 0, 16384, 2048, 512);
  // out = x1 + m1 @ W2 + b2
  gemm_bt<7><<<dim3(128, 4, 1), 256, 0, stream>>>(m1, 2048, 0, W2t, 2048, 0,
                                                  b2, nullptr, nullptr, x1h, nullptr,
                                                  (float*)d_out, 512, 0, 16384, 512, 2048);
}